// Round 7
// baseline (53.327 us; speedup 1.0000x reference)
//
#include <hip/hip_runtime.h>

// out[b, i*4+p, j*4+q] = sum_k w[p*4+q][k] * patch(b,i,j)[k],  k = kh*16+kw
// MFMA 16x16x32 bf16, A = weights (regs), B = patches loaded DIRECTLY from global:
// lane's B-fragment = 8 contiguous kw at one row = one 32B fp32 segment. No LDS.
// Block: 256 thr / 4 waves; wave wv owns patch rows it*16+wv*4..+3, 16 patch cols.
// R7 = R6 with inline-asm cvt_pk replaced by pure-C RNE f2bf (A/B isolating the asm).

typedef __attribute__((ext_vector_type(8))) short short8;
typedef __attribute__((ext_vector_type(4))) float f32x4;

__device__ __forceinline__ unsigned short f2bf(float f) {
    unsigned int u = __builtin_bit_cast(unsigned int, f);
    u = (u + 0x7fffu + ((u >> 16) & 1u)) >> 16;   // RNE
    return (unsigned short)u;
}

__device__ __forceinline__ short8 cvt8c(float4 v0, float4 v1) {
    short8 r;
    r[0] = (short)f2bf(v0.x); r[1] = (short)f2bf(v0.y);
    r[2] = (short)f2bf(v0.z); r[3] = (short)f2bf(v0.w);
    r[4] = (short)f2bf(v1.x); r[5] = (short)f2bf(v1.y);
    r[6] = (short)f2bf(v1.z); r[7] = (short)f2bf(v1.w);
    return r;
}

__global__ __launch_bounds__(256, 4)
void conv_direct2(const float* __restrict__ x,
                  const float* __restrict__ w,
                  float* __restrict__ out) {
    const int tid  = threadIdx.x;
    const int lane = tid & 63;
    const int wv   = tid >> 6;
    const int bx   = blockIdx.x;
    const int jt   = bx & 7;            // j-tile: patch cols jt*16..+15
    const int it   = bx >> 3;           // i-tile: patch rows it*16..+15
    const int b    = blockIdx.y;

    const float* xb = x + (size_t)b * (1024 * 1024);

    const int m  = lane & 15;           // patch col within tile (and o for weights)
    const int kb = (lane >> 4) & 1;     // kw block
    const int hi = lane >> 5;           // kh parity
    const int p  = lane >> 4;           // output sub-row in epilogue

    // ---- weight fragments (A operand): lane holds w[o=lane&15][s*32+(lane>>4)*8+r]
    short8 wfrag[8];
    #pragma unroll
    for (int s = 0; s < 8; ++s) {
        const float* wp = w + m * 256 + s * 32 + (lane >> 4) * 8;
        float4 w0 = *(const float4*)wp;
        float4 w1 = *(const float4*)(wp + 4);
        wfrag[s] = cvt8c(w0, w1);
    }

    // per-lane float offset within the x image: row parity + column
    int colf = jt * 128 + m * 8 + kb * 8;
    if (colf > 1016) colf = 1016;            // edge clamp (only jp==127 lanes)
    const int loff = hi * 1024 + colf;
    const int jp   = jt * 16 + m;

    #pragma unroll 1
    for (int t = 0; t < 4; ++t) {
        const int ip = it * 16 + wv * 4 + t;
        int r0 = ip * 8;
        if (r0 > 1008) r0 = 1008;            // edge clamp (only ip==127)
        const float* base = xb + (size_t)r0 * 1024 + loff;

        // issue all 16 loads (independent; compiler emits counted vmcnt)
        float4 lv[16];
        #pragma unroll
        for (int s = 0; s < 8; ++s) {
            const float* rp = base + s * 2048;   // +2 rows per s
            lv[2 * s]     = *(const float4*)rp;
            lv[2 * s + 1] = *(const float4*)(rp + 4);
        }

        f32x4 acc = {0.f, 0.f, 0.f, 0.f};
        #pragma unroll
        for (int s = 0; s < 8; ++s) {
            short8 bfr = cvt8c(lv[2 * s], lv[2 * s + 1]);
            acc = __builtin_amdgcn_mfma_f32_16x16x32_bf16(wfrag[s], bfr, acc, 0, 0, 0);
        }

        if (ip < 127 && jp < 127) {
            float* op = out + (size_t)b * (508 * 508) + (ip * 4 + p) * 508 + jp * 4;
            *(float4*)op = *(float4*)&acc;
        }
    }
}

extern "C" void kernel_launch(void* const* d_in, const int* in_sizes, int n_in,
                              void* d_out, int out_size, void* d_ws, size_t ws_size,
                              hipStream_t stream) {
    const float* x = (const float*)d_in[0];
    const float* w = (const float*)d_in[1];
    float* out = (float*)d_out;
    dim3 grid(64, 32);   // (it*8 + jt, batch)
    conv_direct2<<<grid, dim3(256, 1, 1), 0, stream>>>(x, w, out);
}

// Round 8
// 42.753 us; speedup vs baseline: 1.2473x; 1.2473x over previous
//
#include <hip/hip_runtime.h>

// out[b, i*4+p, j*4+q] = sum_k w[p*4+q][k] * patch(b,i,j)[k],  k = kh*16+kw
// MFMA 16x16x32 bf16, A = weights (regs), B = patches loaded DIRECTLY from global.
// R8 = R7 + 2-deep software pipeline at half-tile (K=128) granularity:
//   while computing half n, halves n+1 and n+2 are in flight (~16 float4/thread).
// Block: 256 thr / 4 waves; wave wv owns patch rows it*16+wv*4..+3, 16 patch cols.

typedef __attribute__((ext_vector_type(8))) short short8;
typedef __attribute__((ext_vector_type(4))) float f32x4;

__device__ __forceinline__ unsigned short f2bf(float f) {
    unsigned int u = __builtin_bit_cast(unsigned int, f);
    u = (u + 0x7fffu + ((u >> 16) & 1u)) >> 16;   // RNE
    return (unsigned short)u;
}

__device__ __forceinline__ short8 cvt8c(float4 v0, float4 v1) {
    short8 r;
    r[0] = (short)f2bf(v0.x); r[1] = (short)f2bf(v0.y);
    r[2] = (short)f2bf(v0.z); r[3] = (short)f2bf(v0.w);
    r[4] = (short)f2bf(v1.x); r[5] = (short)f2bf(v1.y);
    r[6] = (short)f2bf(v1.z); r[7] = (short)f2bf(v1.w);
    return r;
}

__global__ __launch_bounds__(256, 3)
void conv_pipe(const float* __restrict__ x,
               const float* __restrict__ w,
               float* __restrict__ out) {
    const int tid  = threadIdx.x;
    const int lane = tid & 63;
    const int wv   = tid >> 6;
    const int bx   = blockIdx.x;
    const int jt   = bx & 7;            // j-tile: patch cols jt*16..+15
    const int it   = bx >> 3;           // i-tile: patch rows it*16..+15
    const int b    = blockIdx.y;

    const float* xb = x + (size_t)b * (1024 * 1024);

    const int m  = lane & 15;           // patch col within tile (and o for weights)
    const int kb = (lane >> 4) & 1;     // kw block
    const int hi = lane >> 5;           // kh parity
    const int p  = lane >> 4;           // output sub-row in epilogue

    // ---- weight fragments (A operand): lane holds w[o=lane&15][s*32+(lane>>4)*8+r]
    short8 wfrag[8];
    #pragma unroll
    for (int s = 0; s < 8; ++s) {
        const float* wp = w + m * 256 + s * 32 + (lane >> 4) * 8;
        wfrag[s] = cvt8c(*(const float4*)wp, *(const float4*)(wp + 4));
    }

    int colf = jt * 128 + m * 8 + kb * 8;
    if (colf > 1016) colf = 1016;            // edge clamp (only jp==127 lanes, masked)
    const int jp    = jt * 16 + m;
    const int iband = it * 16 + wv * 4;

    // half-tile (t, h): 8 float4 at rows r0(t)+hi+8h+2u (u=0..3), cols colf..+7
#define ROWPTR(t, h) \
    (xb + (size_t)((((iband + (t)) * 8 > 1008) ? 1008 : (iband + (t)) * 8) + hi + 8 * (h)) * 1024 + colf)

#define ISSUE(buf, t, h) do {                                   \
        const float* _bp = ROWPTR(t, h);                        \
        _Pragma("unroll")                                       \
        for (int _u = 0; _u < 4; ++_u) {                        \
            buf[2 * _u]     = *(const float4*)(_bp + _u * 2048);      \
            buf[2 * _u + 1] = *(const float4*)(_bp + _u * 2048 + 4);  \
        }                                                       \
    } while (0)

#define COMP(buf, h) do {                                       \
        _Pragma("unroll")                                       \
        for (int _u = 0; _u < 4; ++_u) {                        \
            short8 _f = cvt8c(buf[2 * _u], buf[2 * _u + 1]);    \
            acc = __builtin_amdgcn_mfma_f32_16x16x32_bf16(      \
                      wfrag[(h) * 4 + _u], _f, acc, 0, 0, 0);   \
        }                                                       \
    } while (0)

    float4 A[8], B[8];
    f32x4 acc;

    ISSUE(A, 0, 0);        // half (0,0) in flight
    ISSUE(B, 0, 1);        // half (0,1) in flight

    #pragma unroll
    for (int t = 0; t < 4; ++t) {
        acc = (f32x4){0.f, 0.f, 0.f, 0.f};
        COMP(A, 0);                         // waits only on A (B stays in flight)
        if (t < 3) ISSUE(A, t + 1, 0);      // refill A before touching B
        COMP(B, 1);
        if (t < 3) ISSUE(B, t + 1, 1);

        const int ip = iband + t;
        if (ip < 127 && jp < 127) {
            float* op = out + (size_t)b * (508 * 508) + (ip * 4 + p) * 508 + jp * 4;
            *(float4*)op = *(float4*)&acc;
        }
    }
#undef ROWPTR
#undef ISSUE
#undef COMP
}

extern "C" void kernel_launch(void* const* d_in, const int* in_sizes, int n_in,
                              void* d_out, int out_size, void* d_ws, size_t ws_size,
                              hipStream_t stream) {
    const float* x = (const float*)d_in[0];
    const float* w = (const float*)d_in[1];
    float* out = (float*)d_out;
    dim3 grid(64, 32);   // (it*8 + jt, batch)
    conv_pipe<<<grid, dim3(256, 1, 1), 0, stream>>>(x, w, out);
}